// Round 12
// baseline (106.481 us; speedup 1.0000x reference)
//
#include <hip/hip_runtime.h>
#include <hip/hip_bf16.h>

#define B_ 2
#define T_ 2048
#define DM_ 1024
#define H_ 16
#define DH_ 64
// softmax computed in exp2 units: fold log2(e)/sqrt(1024) into Q
#define QSCALE 0.045084220027780106f

typedef unsigned short u16;
typedef unsigned int u32;
typedef __attribute__((ext_vector_type(2))) unsigned int u32x2;
typedef __attribute__((ext_vector_type(4))) unsigned int u32x4;
typedef __attribute__((ext_vector_type(4))) float f32x4v;
typedef __attribute__((ext_vector_type(8))) short bf16x8;
typedef __attribute__((ext_vector_type(4))) float f32x4;
typedef __attribute__((ext_vector_type(16))) float f32x16;

__device__ __forceinline__ u16 f2bf(float f) {
    u32 u = __float_as_uint(f);
    return (u16)((u + 0x7FFF + ((u >> 16) & 1)) >> 16);
}
__device__ __forceinline__ float bf2f(u16 h) {
    return __uint_as_float(((u32)h) << 16);
}
__device__ __forceinline__ float exp2_fast(float x) {
    float r;
    asm("v_exp_f32 %0, %1" : "=v"(r) : "v"(x));
    return r;
}
__device__ __forceinline__ u32 cvtpk_bf16(float lo, float hi) {
    u32 r;
    asm("v_cvt_pk_bf16_f32 %0, %1, %2" : "=v"(r) : "v"(lo), "v"(hi));
    return r;
}

// LDS rows are 128B with 16B-granule XOR swizzle: byte = row*128 + ((c16 ^ (row&7))<<4)
__device__ __forceinline__ const bf16x8* frag_at(const u16* base, int row, int c16) {
    return (const bf16x8*)((const char*)base + row * 128 + ((c16 ^ (row & 7)) << 4));
}

// ---------------- merged weight split ----------------
__global__ __launch_bounds__(256) void wsplit_all(
    const float* __restrict__ Wq, const float* __restrict__ Wk,
    const float* __restrict__ Wv, const float* __restrict__ Wp,
    u16* __restrict__ W6, u16* __restrict__ Wh, u16* __restrict__ Wl)
{
    const int i = blockIdx.x * 256 + threadIdx.x;
    if (i < DM_ * DM_) {
        const float w = Wp[i];
        const u16 hi = f2bf(w);
        Wh[i] = hi;
        Wl[i] = f2bf(w - bf2f(hi));
    } else {
        const int j = i - DM_ * DM_;          // 0..12287
        const int mat = j >> 12, idx = j & 4095;
        const float w = (mat == 0) ? Wq[idx] : (mat == 1) ? Wk[idx] : Wv[idx];
        const u16 hi = f2bf(w);
        W6[(mat * 2) * 4096 + idx] = hi;
        W6[(mat * 2 + 1) * 4096 + idx] = f2bf(w - bf2f(hi));
    }
}

// ---------------- QKV projection via MFMA (split-bf16, fp32-grade) ----------------
__global__ __launch_bounds__(256) void qkv_mfma(
    const float* __restrict__ x,
    const float* __restrict__ bq, const float* __restrict__ bk,
    const float* __restrict__ bv, const u16* __restrict__ W6,
    u16* __restrict__ Q, u16* __restrict__ K, u16* __restrict__ VT)
{
    __shared__ u16 Ws[6 * 4096];   // 48KB

    const int tid = threadIdx.x;
    const int wid = tid >> 6;
    const int lane = tid & 63;
    const int li = lane & 15, g = lane >> 4;

    const int bh = blockIdx.x >> 4;
    const int t0 = (blockIdx.x & 15) * 128;
    const int b = bh >> 4, h = bh & 15;
    const int tw0 = t0 + wid * 32;

    #pragma unroll
    for (int j = 0; j < 12; ++j) {
        const int gi = j * 256 + tid;
        const int tile = gi >> 9;
        const int t16 = gi & 511;
        const int r = t16 >> 3, c16 = t16 & 7;
        const int c16s = c16 ^ (r & 7);
        __builtin_amdgcn_global_load_lds(
            (const __attribute__((address_space(1))) u32*)((const char*)W6 + tile * 8192 + r * 128 + (c16s << 4)),
            (__attribute__((address_space(3))) u32*)((char*)Ws + gi * 16),
            16, 0, 0);
    }

    const float* xb = x + ((size_t)b * T_) * DM_ + h * 64;
    f32x4v xr[2][2][2];
    #pragma unroll
    for (int mt = 0; mt < 2; ++mt)
        #pragma unroll
        for (int kt = 0; kt < 2; ++kt) {
            const float* p = xb + (size_t)(tw0 + 16 * mt + li) * DM_ + kt * 32 + g * 8;
            xr[mt][kt][0] = *(const f32x4v*)p;
            xr[mt][kt][1] = *(const f32x4v*)(p + 4);
        }

    float bq_r[4], bk_r[4], bv_r[4][4];
    #pragma unroll
    for (int nt = 0; nt < 4; ++nt) { bq_r[nt] = bq[16 * nt + li]; bk_r[nt] = bk[16 * nt + li]; }
    #pragma unroll
    for (int vd = 0; vd < 4; ++vd)
        #pragma unroll
        for (int rg = 0; rg < 4; ++rg) bv_r[vd][rg] = bv[16 * vd + 4 * g + rg];

    __syncthreads();

    bf16x8 xhf[2][2], xlf[2][2];
    #pragma unroll
    for (int mt = 0; mt < 2; ++mt)
        #pragma unroll
        for (int kt = 0; kt < 2; ++kt) {
            u32 hw[4], lw[4];
            #pragma unroll
            for (int q2 = 0; q2 < 2; ++q2) {
                const f32x4v v = xr[mt][kt][q2];
                const u32 p0 = cvtpk_bf16(v[0], v[1]);
                const u32 p1 = cvtpk_bf16(v[2], v[3]);
                const float l0 = v[0] - __uint_as_float(p0 << 16);
                const float l1 = v[1] - __uint_as_float(p0 & 0xFFFF0000u);
                const float l2 = v[2] - __uint_as_float(p1 << 16);
                const float l3 = v[3] - __uint_as_float(p1 & 0xFFFF0000u);
                hw[q2 * 2] = p0; hw[q2 * 2 + 1] = p1;
                lw[q2 * 2] = cvtpk_bf16(l0, l1);
                lw[q2 * 2 + 1] = cvtpk_bf16(l2, l3);
            }
            xhf[mt][kt] = *(const bf16x8*)hw;
            xlf[mt][kt] = *(const bf16x8*)lw;
        }

    const u16* Wqh = Ws;
    const u16* Wql = Ws + 4096;
    const u16* Wkh = Ws + 8192;
    const u16* Wkl = Ws + 12288;
    const u16* Wvh = Ws + 16384;
    const u16* Wvl = Ws + 20480;

    const size_t qk_base = ((size_t)bh * T_) * DH_;

    // ---- Q ----
    {
        f32x4 acc[2][4];
        #pragma unroll
        for (int mt = 0; mt < 2; ++mt)
            #pragma unroll
            for (int nt = 0; nt < 4; ++nt) acc[mt][nt] = (f32x4){0.f, 0.f, 0.f, 0.f};
        #pragma unroll
        for (int nt = 0; nt < 4; ++nt)
            #pragma unroll
            for (int kt = 0; kt < 2; ++kt) {
                const bf16x8 wh = *frag_at(Wqh, 16 * nt + li, 4 * kt + g);
                const bf16x8 wl = *frag_at(Wql, 16 * nt + li, 4 * kt + g);
                #pragma unroll
                for (int mt = 0; mt < 2; ++mt) {
                    acc[mt][nt] = __builtin_amdgcn_mfma_f32_16x16x32_bf16(xhf[mt][kt], wh, acc[mt][nt], 0, 0, 0);
                    acc[mt][nt] = __builtin_amdgcn_mfma_f32_16x16x32_bf16(xlf[mt][kt], wh, acc[mt][nt], 0, 0, 0);
                    acc[mt][nt] = __builtin_amdgcn_mfma_f32_16x16x32_bf16(xhf[mt][kt], wl, acc[mt][nt], 0, 0, 0);
                }
            }
        #pragma unroll
        for (int mt = 0; mt < 2; ++mt)
            #pragma unroll
            for (int rg = 0; rg < 4; ++rg) {
                const int t = tw0 + 16 * mt + 4 * g + rg;
                #pragma unroll
                for (int nt = 0; nt < 4; ++nt)
                    Q[qk_base + (size_t)t * DH_ + 16 * nt + li] =
                        f2bf((acc[mt][nt][rg] + bq_r[nt]) * QSCALE);
            }
    }

    // ---- K ----
    {
        f32x4 acc[2][4];
        #pragma unroll
        for (int mt = 0; mt < 2; ++mt)
            #pragma unroll
            for (int nt = 0; nt < 4; ++nt) acc[mt][nt] = (f32x4){0.f, 0.f, 0.f, 0.f};
        #pragma unroll
        for (int nt = 0; nt < 4; ++nt)
            #pragma unroll
            for (int kt = 0; kt < 2; ++kt) {
                const bf16x8 wh = *frag_at(Wkh, 16 * nt + li, 4 * kt + g);
                const bf16x8 wl = *frag_at(Wkl, 16 * nt + li, 4 * kt + g);
                #pragma unroll
                for (int mt = 0; mt < 2; ++mt) {
                    acc[mt][nt] = __builtin_amdgcn_mfma_f32_16x16x32_bf16(xhf[mt][kt], wh, acc[mt][nt], 0, 0, 0);
                    acc[mt][nt] = __builtin_amdgcn_mfma_f32_16x16x32_bf16(xlf[mt][kt], wh, acc[mt][nt], 0, 0, 0);
                    acc[mt][nt] = __builtin_amdgcn_mfma_f32_16x16x32_bf16(xhf[mt][kt], wl, acc[mt][nt], 0, 0, 0);
                }
            }
        #pragma unroll
        for (int mt = 0; mt < 2; ++mt)
            #pragma unroll
            for (int rg = 0; rg < 4; ++rg) {
                const int t = tw0 + 16 * mt + 4 * g + rg;
                #pragma unroll
                for (int nt = 0; nt < 4; ++nt)
                    K[qk_base + (size_t)t * DH_ + 16 * nt + li] =
                        f2bf(acc[mt][nt][rg] + bk_r[nt]);
            }
    }

    // ---- V (swapped) -> V^T ----
    {
        f32x4 acc[4][2];
        #pragma unroll
        for (int vd = 0; vd < 4; ++vd)
            #pragma unroll
            for (int tc = 0; tc < 2; ++tc) acc[vd][tc] = (f32x4){0.f, 0.f, 0.f, 0.f};
        #pragma unroll
        for (int vd = 0; vd < 4; ++vd)
            #pragma unroll
            for (int kt = 0; kt < 2; ++kt) {
                const bf16x8 ah = *frag_at(Wvh, 16 * vd + li, 4 * kt + g);
                const bf16x8 al = *frag_at(Wvl, 16 * vd + li, 4 * kt + g);
                #pragma unroll
                for (int tc = 0; tc < 2; ++tc) {
                    acc[vd][tc] = __builtin_amdgcn_mfma_f32_16x16x32_bf16(ah, xhf[tc][kt], acc[vd][tc], 0, 0, 0);
                    acc[vd][tc] = __builtin_amdgcn_mfma_f32_16x16x32_bf16(al, xhf[tc][kt], acc[vd][tc], 0, 0, 0);
                    acc[vd][tc] = __builtin_amdgcn_mfma_f32_16x16x32_bf16(ah, xlf[tc][kt], acc[vd][tc], 0, 0, 0);
                }
            }
        u16* VTb = VT + (size_t)bh * DH_ * T_;
        #pragma unroll
        for (int vd = 0; vd < 4; ++vd)
            #pragma unroll
            for (int rg = 0; rg < 4; ++rg) {
                const int d = 16 * vd + 4 * g + rg;
                #pragma unroll
                for (int tc = 0; tc < 2; ++tc)
                    VTb[(size_t)d * T_ + tw0 + 16 * tc + li] =
                        f2bf(acc[vd][tc][rg] + bv_r[vd][rg]);
            }
    }
}

// ---------------- MFMA flash attention: 32x32, split-KV x2, pipelined ----------------
// grid = 1024: (bh,kvh) = flat&63 (XCD-grouped), q-chunk = flat>>6.
// Per-iter schedule: bar -> stage(K_{i+2}, V_{i+1}) -> QK(i+1) -> softmax(i)+PV(i).
// No max tracking (exp2-unit S bounded); split-KV partials are exactly additive.
// LDS map: K0 @0, K1 @8192, V0 @16384, V1 @24576.
__global__ __launch_bounds__(256) void attn_mfma(
    const u16* __restrict__ Q, const u16* __restrict__ K,
    const u16* __restrict__ VT, float* __restrict__ OP, float* __restrict__ LP)
{
    __shared__ char smem[32768];

    const int tid = threadIdx.x;
    const int wid = tid >> 6;              // 0..3
    const int lane = tid & 63;
    const int l = lane & 31, h = lane >> 5;
    const int flat = blockIdx.x;
    const int gid = flat & 63;             // locality group: same XCD
    const int bh = gid >> 1, kvh = gid & 1;
    const int qx = flat >> 6;              // 0..15
    const int q0 = qx * 128 + wid * 32;

    const size_t bhoff = (size_t)bh * T_ * DH_;

    // Q fragments (B operand): qf[kt] holds Q[q0+l][16kt+8h .. +7]
    bf16x8 qf[4];
    {
        const u16* Qp = Q + bhoff + (size_t)(q0 + l) * DH_ + 8 * h;
        #pragma unroll
        for (int kt = 0; kt < 4; ++kt)
            qf[kt] = *(const bf16x8*)(Qp + 16 * kt);
    }

    f32x16 o0 = {}, o1 = {};       // O^T[d][q=l] partial (unnormalized)
    f32x16 s0A = {}, s1A = {}, s0B = {}, s1B = {};
    float l_part = 0.f;

    // hoisted ds_read lane bases
    const char* ldsR[4];
    #pragma unroll
    for (int kt = 0; kt < 4; ++kt)
        ldsR[kt] = smem + l * 128 + ((((2 * kt + h) ^ (l & 7))) << 4);

    // staging pointers (pre-swizzled source, linear LDS dest); 16 tiles of this kv half
    const int sl_r = lane >> 3;
    const int sl_c = (lane & 7) ^ sl_r;
    const char* kgp0 = (const char*)(K + bhoff) + kvh * 131072 + (16 * wid + sl_r) * 128 + (sl_c << 4);
    const char* kgp1 = kgp0 + 8 * 128;
    const char* vgp0 = (const char*)(VT + (size_t)bh * DH_ * T_) + kvh * 2048 + (size_t)(16 * wid + sl_r) * (T_ * 2) + (sl_c << 4);
    const char* vgp1 = vgp0 + (size_t)8 * (T_ * 2);
    const int kdst = 16 * wid * 128 + lane * 16;

#define STAGE_K(DST)                                                                     \
    {                                                                                    \
        __builtin_amdgcn_global_load_lds(                                                \
            (const __attribute__((address_space(1))) u32*)kgp0,                          \
            (__attribute__((address_space(3))) u32*)(smem + (DST) + kdst), 16, 0, 0);    \
        __builtin_amdgcn_global_load_lds(                                                \
            (const __attribute__((address_space(1))) u32*)kgp1,                          \
            (__attribute__((address_space(3))) u32*)(smem + (DST) + kdst + 1024), 16, 0, 0); \
        kgp0 += 8192; kgp1 += 8192;                                                      \
    }
#define STAGE_V(DST)                                                                     \
    {                                                                                    \
        __builtin_amdgcn_global_load_lds(                                                \
            (const __attribute__((address_space(1))) u32*)vgp0,                          \
            (__attribute__((address_space(3))) u32*)(smem + (DST) + kdst), 16, 0, 0);    \
        __builtin_amdgcn_global_load_lds(                                                \
            (const __attribute__((address_space(1))) u32*)vgp1,                          \
            (__attribute__((address_space(3))) u32*)(smem + (DST) + kdst + 1024), 16, 0, 0); \
        vgp0 += 128; vgp1 += 128;                                                        \
    }

// QK(i): S = K-tile x Q; pinned before the softmax of the previous tile
#define QK_BLOCK(KB, S0, S1)                                                             \
    {                                                                                    \
        S0 = (f32x16){}; S1 = (f32x16){};                                                \
        __builtin_amdgcn_s_setprio(1);                                                   \
        _Pragma("unroll")                                                                \
        for (int kt = 0; kt < 4; ++kt) {                                                 \
            const bf16x8 kf0 = *(const bf16x8*)(ldsR[kt] + (KB));                        \
            const bf16x8 kf1 = *(const bf16x8*)(ldsR[kt] + (KB) + 4096);                 \
            S0 = __builtin_amdgcn_mfma_f32_32x32x16_bf16(kf0, qf[kt], S0, 0, 0, 0);      \
            S1 = __builtin_amdgcn_mfma_f32_32x32x16_bf16(kf1, qf[kt], S1, 0, 0, 0);      \
        }                                                                                \
        __builtin_amdgcn_s_setprio(0);                                                   \
        __builtin_amdgcn_sched_barrier(0);                                               \
    }

// VB is the ABSOLUTE LDS byte offset of the V buffer (16384 = V0, 24576 = V1).
#define SOFTMAX_PV(S0, S1, VB)                                                           \
    {                                                                                    \
        float lacc = 0.f;                                                                \
        _Pragma("unroll")                                                                \
        for (int r = 0; r < 16; ++r) { S0[r] = exp2_fast(S0[r]); lacc += S0[r]; }        \
        _Pragma("unroll")                                                                \
        for (int r = 0; r < 16; ++r) { S1[r] = exp2_fast(S1[r]); lacc += S1[r]; }        \
        l_part += lacc;                                                                  \
        __builtin_amdgcn_s_setprio(1);                                                   \
        _Pragma("unroll")                                                                \
        for (int kt = 0; kt < 4; ++kt) {                                                 \
            const int rb = (kt & 1) * 8;                                                 \
            u32 w0, w1, w2, w3;                                                          \
            if (kt < 2) {                                                                \
                w0 = cvtpk_bf16(S0[rb + 0], S0[rb + 1]);                                 \
                w1 = cvtpk_bf16(S0[rb + 2], S0[rb + 3]);                                 \
                w2 = cvtpk_bf16(S0[rb + 4], S0[rb + 5]);                                 \
                w3 = cvtpk_bf16(S0[rb + 6], S0[rb + 7]);                                 \
            } else {                                                                     \
                w0 = cvtpk_bf16(S1[rb + 0], S1[rb + 1]);                                 \
                w1 = cvtpk_bf16(S1[rb + 2], S1[rb + 3]);                                 \
                w2 = cvtpk_bf16(S1[rb + 4], S1[rb + 5]);                                 \
                w3 = cvtpk_bf16(S1[rb + 6], S1[rb + 7]);                                 \
            }                                                                            \
            asm("v_permlane32_swap_b32 %0, %1" : "+v"(w0), "+v"(w2));                    \
            asm("v_permlane32_swap_b32 %0, %1" : "+v"(w1), "+v"(w3));                    \
            u32x4 pw; pw[0] = w0; pw[1] = w1; pw[2] = w2; pw[3] = w3;                    \
            const bf16x8 pf = __builtin_bit_cast(bf16x8, pw);                            \
            const bf16x8 vf0 = *(const bf16x8*)(ldsR[kt] + (VB));                        \
            const bf16x8 vf1 = *(const bf16x8*)(ldsR[kt] + (VB) + 4096);                 \
            o0 = __builtin_amdgcn_mfma_f32_32x32x16_bf16(vf0, pf, o0, 0, 0, 0);          \
            o1 = __builtin_amdgcn_mfma_f32_32x32x16_bf16(vf1, pf, o1, 0, 0, 0);          \
        }                                                                                \
        __builtin_amdgcn_s_setprio(0);                                                   \
    }

    // prologue: tile0 -> K0,V0; QK(0); tile1 K -> K1
    STAGE_K(0);
    STAGE_V(16384);
    __syncthreads();
    QK_BLOCK(0, s0A, s1A);
    STAGE_K(8192);

    for (int it = 0; it < 16; it += 2) {
        __syncthreads();                       // drains K(it+1); all waves past QK(it), PV(it-1)
        if (it + 2 < 16) STAGE_K(0);           // tile it+2 -> K0
        STAGE_V(24576);                        // tile it+1 -> V1
        QK_BLOCK(8192, s0B, s1B);              // QK(it+1) from K1 (overlaps softmax below)
        SOFTMAX_PV(s0A, s1A, 16384);           // tile it from V0

        __syncthreads();                       // drains K(it+2), V(it+1)
        if (it + 3 < 16) STAGE_K(8192);        // tile it+3 -> K1
        if (it + 2 < 16) {
            STAGE_V(16384);                    // tile it+2 -> V0
            QK_BLOCK(0, s0A, s1A);             // QK(it+2) from K0
        }
        SOFTMAX_PV(s0B, s1B, 24576);           // tile it+1 from V1
    }
#undef STAGE_K
#undef STAGE_V
#undef QK_BLOCK
#undef SOFTMAX_PV

    // partial l per q-row (sum over this kv half)
    const float lt = l_part + __shfl_xor(l_part, 32);

    __syncthreads();   // done with K/V LDS; reuse as per-wave epilogue scratch

    // O^T -> O transpose via LDS, f32, 16B-granule XOR swizzle over 16 granules/row
    float* ew = (float*)(smem + wid * 8192);   // [32 q][256B]
    #pragma unroll
    for (int db = 0; db < 2; ++db) {
        #pragma unroll
        for (int rr = 0; rr < 4; ++rr) {
            f32x4v v;
            if (db == 0) {
                v[0] = o0[4 * rr + 0]; v[1] = o0[4 * rr + 1];
                v[2] = o0[4 * rr + 2]; v[3] = o0[4 * rr + 3];
            } else {
                v[0] = o1[4 * rr + 0]; v[1] = o1[4 * rr + 1];
                v[2] = o1[4 * rr + 2]; v[3] = o1[4 * rr + 3];
            }
            const int gr = (2 * rr + h + 8 * db) ^ (l & 15);
            *(f32x4v*)((char*)ew + l * 256 + (gr << 4)) = v;
        }
    }
    // per-wave private region: lgkmcnt ordering suffices

    const size_t rowbase = (size_t)bh * T_ + q0;
    float* opb = OP + (size_t)kvh * (65536ull * 64);
    const int ql = lane >> 1, hf = lane & 1;
    float* oprow = opb + (rowbase + ql) * 64 + hf * 32;
    #pragma unroll
    for (int j = 0; j < 8; ++j) {
        const int gr = (hf * 8 + j) ^ (ql & 15);
        const f32x4v v = *(const f32x4v*)((char*)ew + ql * 256 + (gr << 4));
        *(f32x4v*)(oprow + 4 * j) = v;
    }
    if (h == 0) LP[kvh * 65536 + rowbase + l] = lt;
}

// ---------------- combine: O = (O0+O1)/(l0+l1), split hi/lo bf16 ----------------
__global__ __launch_bounds__(256) void combine_kernel(
    const float* __restrict__ OP, const float* __restrict__ LP,
    u16* __restrict__ Ah, u16* __restrict__ Al)
{
    const int tid = threadIdx.x;
    const int row = blockIdx.x * 64 + (tid >> 2);     // bh*2048 + q
    const int dq = (tid & 3) * 16;
    const float inv = 1.0f / (LP[row] + LP[65536 + row]);
    const float* p0 = OP + (size_t)row * 64 + dq;
    const float* p1 = p0 + 65536ull * 64;
    const int bh = row >> 11, q = row & 2047;
    const int b = bh >> 4, hh = bh & 15;
    const size_t gidx = ((size_t)(b * T_ + q)) * DM_ + hh * 64 + dq;

    u32 hw[8], lw[8];
    #pragma unroll
    for (int j = 0; j < 4; ++j) {
        const f32x4v a = *(const f32x4v*)(p0 + 4 * j);
        const f32x4v c = *(const f32x4v*)(p1 + 4 * j);
        const float v0 = (a[0] + c[0]) * inv;
        const float v1 = (a[1] + c[1]) * inv;
        const float v2 = (a[2] + c[2]) * inv;
        const float v3 = (a[3] + c[3]) * inv;
        const u32 h0 = cvtpk_bf16(v0, v1);
        const u32 h1 = cvtpk_bf16(v2, v3);
        const float r0 = v0 - __uint_as_float(h0 << 16);
        const float r1 = v1 - __uint_as_float(h0 & 0xFFFF0000u);
        const float r2 = v2 - __uint_as_float(h1 << 16);
        const float r3 = v3 - __uint_as_float(h1 & 0xFFFF0000u);
        hw[2 * j] = h0; hw[2 * j + 1] = h1;
        lw[2 * j] = cvtpk_bf16(r0, r1);
        lw[2 * j + 1] = cvtpk_bf16(r2, r3);
    }
    u32x4 hv0, hv1, lv0, lv1;
    hv0[0] = hw[0]; hv0[1] = hw[1]; hv0[2] = hw[2]; hv0[3] = hw[3];
    hv1[0] = hw[4]; hv1[1] = hw[5]; hv1[2] = hw[6]; hv1[3] = hw[7];
    lv0[0] = lw[0]; lv0[1] = lw[1]; lv0[2] = lw[2]; lv0[3] = lw[3];
    lv1[0] = lw[4]; lv1[1] = lw[5]; lv1[2] = lw[6]; lv1[3] = lw[7];
    *(u32x4*)(Ah + gidx) = hv0;
    *(u32x4*)(Ah + gidx + 8) = hv1;
    *(u32x4*)(Al + gidx) = lv0;
    *(u32x4*)(Al + gidx + 8) = lv1;
}

// ---------------- Output projection: split-bf16 MFMA GEMM, 8 waves, dbuf ----------------
__global__ __launch_bounds__(512) void proj_mfma(
    const u16* __restrict__ Ah, const u16* __restrict__ Al,
    const u16* __restrict__ Wh, const u16* __restrict__ Wl,
    const float* __restrict__ bp, float* __restrict__ out)
{
    __shared__ char smem[131072];  // 2 x {Ah,Al,Wh,Wl} of 128x64 bf16 (16KB each)

    const int tid = threadIdx.x;
    const int wid = tid >> 6;      // 0..7
    const int lane = tid & 63;
    const int li = lane & 15, g = lane >> 4;
    const int row0 = blockIdx.y * 128, col0 = blockIdx.x * 128;

    const int mat = wid >> 1, half = wid & 1;
    const char* gsrc;
    if (mat == 0)      gsrc = (const char*)(Ah + (size_t)row0 * DM_);
    else if (mat == 1) gsrc = (const char*)(Al + (size_t)row0 * DM_);
    else if (mat == 2) gsrc = (const char*)(Wh + (size_t)col0 * DM_);
    else               gsrc = (const char*)(Wl + (size_t)col0 * DM_);
    const int r_local = half * 64 + (lane >> 3);
    const int c16s = (lane & 7) ^ (lane >> 3);
    const char* gp0 = gsrc + (size_t)r_local * (DM_ * 2) + (c16s << 4);
    const int ldst0 = mat * 16384 + half * 8192;

#define PSTAGE(BUF, STEP)                                                                \
    {                                                                                    \
        _Pragma("unroll")                                                                \
        for (int j = 0; j < 8; ++j) {                                                    \
            __builtin_amdgcn_global_load_lds(                                            \
                (const __attribute__((address_space(1))) u32*)(gp0 + (size_t)(STEP) * 128 + (size_t)j * (8 * DM_ * 2)), \
                (__attribute__((address_space(3))) u32*)(smem + (BUF) + ldst0 + j * 1024),\
                16, 0, 0);                                                               \
        }                                                                                \
    }

    const int wr = wid >> 1, wc = wid & 1;

    f32x4 acc[2][4];
    #pragma unroll
    for (int m = 0; m < 2; ++m)
        #pragma unroll
        for (int n = 0; n < 4; ++n) acc[m][n] = (f32x4){0.f, 0.f, 0.f, 0.f};

    PSTAGE(0, 0);
    for (int step = 0; step < 16; ++step) {
        const int buf = (step & 1) * 65536;
        __syncthreads();
        if (step < 15) PSTAGE(buf ^ 65536, step + 1);

        const u16* pAh = (const u16*)(smem + buf);
        const u16* pAl = (const u16*)(smem + buf + 16384);
        const u16* pWh = (const u16*)(smem + buf + 32768);
        const u16* pWl = (const u16*)(smem + buf + 49152);

        __builtin_amdgcn_s_setprio(1);
        #pragma unroll
        for (int kt = 0; kt < 2; ++kt) {
            bf16x8 ah[2], al[2], wh[4], wl[4];
            #pragma unroll
            for (int m = 0; m < 2; ++m) {
                ah[m] = *frag_at(pAh, wr * 32 + m * 16 + li, kt * 4 + g);
                al[m] = *frag_at(pAl, wr * 32 + m * 16 + li, kt * 4 + g);
            }
            #pragma unroll
            for (int n = 0; n < 4; ++n) {
                wh[n] = *frag_at(pWh, wc * 64 + n * 16 + li, kt * 4 + g);
                wl[n] = *frag_at(pWl, wc * 64 + n * 16 + li, kt * 4 + g);
            }
            #pragma unroll
            for (int m = 0; m < 2; ++m)
                #pragma unroll
                for (int n = 0; n < 4; ++n) {
                    acc[m][n] = __builtin_amdgcn_mfma_f32_16x16x32_bf16(ah[m], wh[n], acc[m][n], 0, 0, 0);
                    acc[m][n] = __builtin_amdgcn_mfma_f32_16x16x32_bf16(al[m], wh[n], acc[m][n], 0, 0, 0);
                    acc[m][n] = __builtin_amdgcn_mfma_f32_16x16x32_bf16(ah[m], wl[n], acc[m][n], 0, 0, 0);
                }
        }
        __builtin_amdgcn_s_setprio(0);
    }
#undef PSTAGE

    const int orow = row0 + wr * 32;
    const int ocol = col0 + wc * 64;
    float bias[4];
    #pragma unroll
    for (int n = 0; n < 4; ++n) bias[n] = bp[ocol + n * 16 + li];
    #pragma unroll
    for (int m = 0; m < 2; ++m)
        #pragma unroll
        for (int n = 0; n < 4; ++n)
            #pragma unroll
            for (int q = 0; q < 4; ++q)
                out[(size_t)(orow + m * 16 + g * 4 + q) * DM_ + ocol + n * 16 + li] =
                    acc[m][n][q] + bias[n];
}

extern "C" void kernel_launch(void* const* d_in, const int* in_sizes, int n_in,
                              void* d_out, int out_size, void* d_ws, size_t ws_size,
                              hipStream_t stream) {
    const float* x  = (const float*)d_in[0];
    const float* Wq = (const float*)d_in[1];
    const float* bq = (const float*)d_in[2];
    const float* Wk = (const float*)d_in[3];
    const float* bk = (const float*)d_in[4];
    const float* Wv = (const float*)d_in[5];
    const float* bv = (const float*)d_in[6];
    const float* Wp = (const float*)d_in[7];
    const float* bp = (const float*)d_in[8];
    float* out = (float*)d_out;

    const size_t n_qkv = (size_t)B_ * H_ * T_ * DH_;   // 4,194,304
    const size_t n_w   = (size_t)DM_ * DM_;            // 1,048,576
    u16* Qb  = (u16*)d_ws;         // aliased as Ah after attn (Q dead)
    u16* Kb  = Qb + n_qkv;         // aliased as Al after attn (K dead)
    u16* VTb = Kb + n_qkv;
    u16* Whb = VTb + n_qkv;
    u16* Wlb = Whb + n_w;
    u16* W6b = Wlb + n_w;          // 24576 elems
    float* OPb = (float*)(W6b + 24576);   // 2 * n_qkv floats (33.5MB)
    float* LPb = OPb + 2 * n_qkv;         // 2 * 65536 floats

    wsplit_all<<<(n_w + 12288) / 256, 256, 0, stream>>>(Wq, Wk, Wv, Wp, W6b, Whb, Wlb);
    qkv_mfma<<<32 * 16, 256, 0, stream>>>(x, bq, bk, bv, W6b, Qb, Kb, VTb);
    attn_mfma<<<1024, 256, 0, stream>>>(Qb, Kb, VTb, OPb, LPb);
    combine_kernel<<<1024, 256, 0, stream>>>(OPb, LPb, Qb, Kb);
    proj_mfma<<<dim3(DM_ / 128, (B_ * T_) / 128), 512, 0, stream>>>(Qb, Kb, Whb, Wlb, bp, out);
}

// Round 13
// 90.124 us; speedup vs baseline: 1.1815x; 1.1815x over previous
//
#include <hip/hip_runtime.h>
#include <hip/hip_bf16.h>

#define B_ 2
#define T_ 2048
#define DM_ 1024
#define H_ 16
#define DH_ 64
// softmax computed in exp2 units: fold log2(e)/sqrt(1024) into Q
#define QSCALE 0.045084220027780106f

typedef unsigned short u16;
typedef unsigned int u32;
typedef __attribute__((ext_vector_type(2))) unsigned int u32x2;
typedef __attribute__((ext_vector_type(4))) unsigned int u32x4;
typedef __attribute__((ext_vector_type(4))) float f32x4v;
typedef __attribute__((ext_vector_type(8))) short bf16x8;
typedef __attribute__((ext_vector_type(4))) float f32x4;
typedef __attribute__((ext_vector_type(16))) float f32x16;

__device__ __forceinline__ u16 f2bf(float f) {
    u32 u = __float_as_uint(f);
    return (u16)((u + 0x7FFF + ((u >> 16) & 1)) >> 16);
}
__device__ __forceinline__ float bf2f(u16 h) {
    return __uint_as_float(((u32)h) << 16);
}
__device__ __forceinline__ float exp2_fast(float x) {
    float r;
    asm("v_exp_f32 %0, %1" : "=v"(r) : "v"(x));
    return r;
}
__device__ __forceinline__ u32 cvtpk_bf16(float lo, float hi) {
    u32 r;
    asm("v_cvt_pk_bf16_f32 %0, %1, %2" : "=v"(r) : "v"(lo), "v"(hi));
    return r;
}

// LDS rows are 128B with 16B-granule XOR swizzle: byte = row*128 + ((c16 ^ (row&7))<<4)
__device__ __forceinline__ const bf16x8* frag_at(const u16* base, int row, int c16) {
    return (const bf16x8*)((const char*)base + row * 128 + ((c16 ^ (row & 7)) << 4));
}

// ---------------- merged weight split ----------------
__global__ __launch_bounds__(256) void wsplit_all(
    const float* __restrict__ Wq, const float* __restrict__ Wk,
    const float* __restrict__ Wv, const float* __restrict__ Wp,
    u16* __restrict__ W6, u16* __restrict__ Wh, u16* __restrict__ Wl)
{
    const int i = blockIdx.x * 256 + threadIdx.x;
    if (i < DM_ * DM_) {
        const float w = Wp[i];
        const u16 hi = f2bf(w);
        Wh[i] = hi;
        Wl[i] = f2bf(w - bf2f(hi));
    } else {
        const int j = i - DM_ * DM_;          // 0..12287
        const int mat = j >> 12, idx = j & 4095;
        const float w = (mat == 0) ? Wq[idx] : (mat == 1) ? Wk[idx] : Wv[idx];
        const u16 hi = f2bf(w);
        W6[(mat * 2) * 4096 + idx] = hi;
        W6[(mat * 2 + 1) * 4096 + idx] = f2bf(w - bf2f(hi));
    }
}

// ---------------- QKV projection via MFMA (split-bf16, fp32-grade) ----------------
__global__ __launch_bounds__(256) void qkv_mfma(
    const float* __restrict__ x,
    const float* __restrict__ bq, const float* __restrict__ bk,
    const float* __restrict__ bv, const u16* __restrict__ W6,
    u16* __restrict__ Q, u16* __restrict__ K, u16* __restrict__ VT)
{
    __shared__ u16 Ws[6 * 4096];   // 48KB

    const int tid = threadIdx.x;
    const int wid = tid >> 6;
    const int lane = tid & 63;
    const int li = lane & 15, g = lane >> 4;

    const int bh = blockIdx.x >> 4;
    const int t0 = (blockIdx.x & 15) * 128;
    const int b = bh >> 4, h = bh & 15;
    const int tw0 = t0 + wid * 32;

    #pragma unroll
    for (int j = 0; j < 12; ++j) {
        const int gi = j * 256 + tid;
        const int tile = gi >> 9;
        const int t16 = gi & 511;
        const int r = t16 >> 3, c16 = t16 & 7;
        const int c16s = c16 ^ (r & 7);
        __builtin_amdgcn_global_load_lds(
            (const __attribute__((address_space(1))) u32*)((const char*)W6 + tile * 8192 + r * 128 + (c16s << 4)),
            (__attribute__((address_space(3))) u32*)((char*)Ws + gi * 16),
            16, 0, 0);
    }

    const float* xb = x + ((size_t)b * T_) * DM_ + h * 64;
    f32x4v xr[2][2][2];
    #pragma unroll
    for (int mt = 0; mt < 2; ++mt)
        #pragma unroll
        for (int kt = 0; kt < 2; ++kt) {
            const float* p = xb + (size_t)(tw0 + 16 * mt + li) * DM_ + kt * 32 + g * 8;
            xr[mt][kt][0] = *(const f32x4v*)p;
            xr[mt][kt][1] = *(const f32x4v*)(p + 4);
        }

    float bq_r[4], bk_r[4], bv_r[4][4];
    #pragma unroll
    for (int nt = 0; nt < 4; ++nt) { bq_r[nt] = bq[16 * nt + li]; bk_r[nt] = bk[16 * nt + li]; }
    #pragma unroll
    for (int vd = 0; vd < 4; ++vd)
        #pragma unroll
        for (int rg = 0; rg < 4; ++rg) bv_r[vd][rg] = bv[16 * vd + 4 * g + rg];

    __syncthreads();

    bf16x8 xhf[2][2], xlf[2][2];
    #pragma unroll
    for (int mt = 0; mt < 2; ++mt)
        #pragma unroll
        for (int kt = 0; kt < 2; ++kt) {
            u32 hw[4], lw[4];
            #pragma unroll
            for (int q2 = 0; q2 < 2; ++q2) {
                const f32x4v v = xr[mt][kt][q2];
                const u32 p0 = cvtpk_bf16(v[0], v[1]);
                const u32 p1 = cvtpk_bf16(v[2], v[3]);
                const float l0 = v[0] - __uint_as_float(p0 << 16);
                const float l1 = v[1] - __uint_as_float(p0 & 0xFFFF0000u);
                const float l2 = v[2] - __uint_as_float(p1 << 16);
                const float l3 = v[3] - __uint_as_float(p1 & 0xFFFF0000u);
                hw[q2 * 2] = p0; hw[q2 * 2 + 1] = p1;
                lw[q2 * 2] = cvtpk_bf16(l0, l1);
                lw[q2 * 2 + 1] = cvtpk_bf16(l2, l3);
            }
            xhf[mt][kt] = *(const bf16x8*)hw;
            xlf[mt][kt] = *(const bf16x8*)lw;
        }

    const u16* Wqh = Ws;
    const u16* Wql = Ws + 4096;
    const u16* Wkh = Ws + 8192;
    const u16* Wkl = Ws + 12288;
    const u16* Wvh = Ws + 16384;
    const u16* Wvl = Ws + 20480;

    const size_t qk_base = ((size_t)bh * T_) * DH_;

    // ---- Q ----
    {
        f32x4 acc[2][4];
        #pragma unroll
        for (int mt = 0; mt < 2; ++mt)
            #pragma unroll
            for (int nt = 0; nt < 4; ++nt) acc[mt][nt] = (f32x4){0.f, 0.f, 0.f, 0.f};
        #pragma unroll
        for (int nt = 0; nt < 4; ++nt)
            #pragma unroll
            for (int kt = 0; kt < 2; ++kt) {
                const bf16x8 wh = *frag_at(Wqh, 16 * nt + li, 4 * kt + g);
                const bf16x8 wl = *frag_at(Wql, 16 * nt + li, 4 * kt + g);
                #pragma unroll
                for (int mt = 0; mt < 2; ++mt) {
                    acc[mt][nt] = __builtin_amdgcn_mfma_f32_16x16x32_bf16(xhf[mt][kt], wh, acc[mt][nt], 0, 0, 0);
                    acc[mt][nt] = __builtin_amdgcn_mfma_f32_16x16x32_bf16(xlf[mt][kt], wh, acc[mt][nt], 0, 0, 0);
                    acc[mt][nt] = __builtin_amdgcn_mfma_f32_16x16x32_bf16(xhf[mt][kt], wl, acc[mt][nt], 0, 0, 0);
                }
            }
        #pragma unroll
        for (int mt = 0; mt < 2; ++mt)
            #pragma unroll
            for (int rg = 0; rg < 4; ++rg) {
                const int t = tw0 + 16 * mt + 4 * g + rg;
                #pragma unroll
                for (int nt = 0; nt < 4; ++nt)
                    Q[qk_base + (size_t)t * DH_ + 16 * nt + li] =
                        f2bf((acc[mt][nt][rg] + bq_r[nt]) * QSCALE);
            }
    }

    // ---- K ----
    {
        f32x4 acc[2][4];
        #pragma unroll
        for (int mt = 0; mt < 2; ++mt)
            #pragma unroll
            for (int nt = 0; nt < 4; ++nt) acc[mt][nt] = (f32x4){0.f, 0.f, 0.f, 0.f};
        #pragma unroll
        for (int nt = 0; nt < 4; ++nt)
            #pragma unroll
            for (int kt = 0; kt < 2; ++kt) {
                const bf16x8 wh = *frag_at(Wkh, 16 * nt + li, 4 * kt + g);
                const bf16x8 wl = *frag_at(Wkl, 16 * nt + li, 4 * kt + g);
                #pragma unroll
                for (int mt = 0; mt < 2; ++mt) {
                    acc[mt][nt] = __builtin_amdgcn_mfma_f32_16x16x32_bf16(xhf[mt][kt], wh, acc[mt][nt], 0, 0, 0);
                    acc[mt][nt] = __builtin_amdgcn_mfma_f32_16x16x32_bf16(xlf[mt][kt], wh, acc[mt][nt], 0, 0, 0);
                    acc[mt][nt] = __builtin_amdgcn_mfma_f32_16x16x32_bf16(xhf[mt][kt], wl, acc[mt][nt], 0, 0, 0);
                }
            }
        #pragma unroll
        for (int mt = 0; mt < 2; ++mt)
            #pragma unroll
            for (int rg = 0; rg < 4; ++rg) {
                const int t = tw0 + 16 * mt + 4 * g + rg;
                #pragma unroll
                for (int nt = 0; nt < 4; ++nt)
                    K[qk_base + (size_t)t * DH_ + 16 * nt + li] =
                        f2bf(acc[mt][nt][rg] + bk_r[nt]);
            }
    }

    // ---- V (swapped) -> V^T ----
    {
        f32x4 acc[4][2];
        #pragma unroll
        for (int vd = 0; vd < 4; ++vd)
            #pragma unroll
            for (int tc = 0; tc < 2; ++tc) acc[vd][tc] = (f32x4){0.f, 0.f, 0.f, 0.f};
        #pragma unroll
        for (int vd = 0; vd < 4; ++vd)
            #pragma unroll
            for (int kt = 0; kt < 2; ++kt) {
                const bf16x8 ah = *frag_at(Wvh, 16 * vd + li, 4 * kt + g);
                const bf16x8 al = *frag_at(Wvl, 16 * vd + li, 4 * kt + g);
                #pragma unroll
                for (int tc = 0; tc < 2; ++tc) {
                    acc[vd][tc] = __builtin_amdgcn_mfma_f32_16x16x32_bf16(ah, xhf[tc][kt], acc[vd][tc], 0, 0, 0);
                    acc[vd][tc] = __builtin_amdgcn_mfma_f32_16x16x32_bf16(al, xhf[tc][kt], acc[vd][tc], 0, 0, 0);
                    acc[vd][tc] = __builtin_amdgcn_mfma_f32_16x16x32_bf16(ah, xlf[tc][kt], acc[vd][tc], 0, 0, 0);
                }
            }
        u16* VTb = VT + (size_t)bh * DH_ * T_;
        #pragma unroll
        for (int vd = 0; vd < 4; ++vd)
            #pragma unroll
            for (int rg = 0; rg < 4; ++rg) {
                const int d = 16 * vd + 4 * g + rg;
                #pragma unroll
                for (int tc = 0; tc < 2; ++tc)
                    VTb[(size_t)d * T_ + tw0 + 16 * tc + li] =
                        f2bf(acc[vd][tc][rg] + bv_r[vd][rg]);
            }
    }
}

// ---------------- MFMA flash attention: 32x32, KVBLK=128, no P-LDS ----------------
// grid = 512 (XCD-swizzled), 4 waves x 32 q-rows. 16 iterations of 128 kv.
// LDS: K dbuf @0/16384 (128 rows x 128B), V dbuf @32768/49152 (2 half-tiles of
// 64 d-rows x 128B each, half n at +n*8192).
__global__ __launch_bounds__(256) void attn_mfma(
    const u16* __restrict__ Q, const u16* __restrict__ K,
    const u16* __restrict__ VT, u16* __restrict__ Ah, u16* __restrict__ Al)
{
    __shared__ char smem[65536];

    const int tid = threadIdx.x;
    const int wid = tid >> 6;              // 0..3
    const int lane = tid & 63;
    const int l = lane & 31, h = lane >> 5;
    const int flat = blockIdx.x;
    const int bh = (flat & 7) + ((flat >> 7) << 3);
    const int qx = (flat >> 3) & 15;
    const int q0 = qx * 128 + wid * 32;

    const size_t bhoff = (size_t)bh * T_ * DH_;

    // Q fragments (B operand): qf[kt] holds Q[q0+l][16kt+8h .. +7]
    bf16x8 qf[4];
    {
        const u16* Qp = Q + bhoff + (size_t)(q0 + l) * DH_ + 8 * h;
        #pragma unroll
        for (int kt = 0; kt < 4; ++kt)
            qf[kt] = *(const bf16x8*)(Qp + 16 * kt);
    }

    f32x16 o0 = {}, o1 = {};       // O^T[d][q=l]
    f32x16 sA, sB, sC, sD;         // S^T sub-blocks kv 0-31,32-63,64-95,96-127
    float l_part = 0.f;

    // hoisted ds_read lane bases: granule (2j+h) ^ (l&7), j=0..3 covers all 8 granules
    const char* ldsR[4];
    #pragma unroll
    for (int j = 0; j < 4; ++j)
        ldsR[j] = smem + l * 128 + ((((2 * j + h) ^ (l & 7))) << 4);

    // staging pointers (pre-swizzled source, linear LDS dest)
    const int sl_r = lane >> 3;
    const int sl_c = (lane & 7) ^ sl_r;
    const char* kgp = (const char*)(K + bhoff) + (32 * wid + sl_r) * 128 + (sl_c << 4);
    const char* vgp = (const char*)(VT + (size_t)bh * DH_ * T_) + (size_t)(16 * wid + sl_r) * (T_ * 2) + (sl_c << 4);
    const int kdst = 32 * wid * 128 + lane * 16;   // 32 K rows per wave
    const int vdst = 16 * wid * 128 + lane * 16;   // 16 V rows per wave per half

#define STAGE(KB_, VB_)                                                                  \
    {                                                                                    \
        _Pragma("unroll")                                                                \
        for (int j = 0; j < 4; ++j)                                                      \
            __builtin_amdgcn_global_load_lds(                                            \
                (const __attribute__((address_space(1))) u32*)(kgp + j * 1024),          \
                (__attribute__((address_space(3))) u32*)(smem + (KB_) + kdst + j * 1024),\
                16, 0, 0);                                                               \
        __builtin_amdgcn_global_load_lds(                                                \
            (const __attribute__((address_space(1))) u32*)vgp,                           \
            (__attribute__((address_space(3))) u32*)(smem + (VB_) + vdst), 16, 0, 0);    \
        __builtin_amdgcn_global_load_lds(                                                \
            (const __attribute__((address_space(1))) u32*)(vgp + 8 * T_ * 2),            \
            (__attribute__((address_space(3))) u32*)(smem + (VB_) + vdst + 1024), 16, 0, 0); \
        __builtin_amdgcn_global_load_lds(                                                \
            (const __attribute__((address_space(1))) u32*)(vgp + 128),                   \
            (__attribute__((address_space(3))) u32*)(smem + (VB_) + 8192 + vdst), 16, 0, 0); \
        __builtin_amdgcn_global_load_lds(                                                \
            (const __attribute__((address_space(1))) u32*)(vgp + 8 * T_ * 2 + 128),      \
            (__attribute__((address_space(3))) u32*)(smem + (VB_) + 8192 + vdst + 1024), 16, 0, 0); \
        kgp += 16384; vgp += 256;                                                        \
    }

// QK for sub-block c (K rows 32c..32c+31): S = K-tile x Q
#define QK(KB_, S, c)                                                                    \
    {                                                                                    \
        S = (f32x16){};                                                                  \
        _Pragma("unroll")                                                                \
        for (int kt = 0; kt < 4; ++kt) {                                                 \
            const bf16x8 kf = *(const bf16x8*)(ldsR[kt] + (KB_) + (c) * 4096);           \
            S = __builtin_amdgcn_mfma_f32_32x32x16_bf16(kf, qf[kt], S, 0, 0, 0);         \
        }                                                                                \
    }

// softmax + PV for sub-block c from S
#define SMPV(S, c, VB_)                                                                  \
    {                                                                                    \
        float lacc = 0.f;                                                                \
        _Pragma("unroll")                                                                \
        for (int r = 0; r < 16; ++r) { S[r] = exp2_fast(S[r]); lacc += S[r]; }           \
        l_part += lacc;                                                                  \
        __builtin_amdgcn_s_setprio(1);                                                   \
        _Pragma("unroll")                                                                \
        for (int ktl = 0; ktl < 2; ++ktl) {                                              \
            const int rb = ktl * 8;                                                      \
            u32 w0 = cvtpk_bf16(S[rb + 0], S[rb + 1]);                                   \
            u32 w1 = cvtpk_bf16(S[rb + 2], S[rb + 3]);                                   \
            u32 w2 = cvtpk_bf16(S[rb + 4], S[rb + 5]);                                   \
            u32 w3 = cvtpk_bf16(S[rb + 6], S[rb + 7]);                                   \
            asm("v_permlane32_swap_b32 %0, %1" : "+v"(w0), "+v"(w2));                    \
            asm("v_permlane32_swap_b32 %0, %1" : "+v"(w1), "+v"(w3));                    \
            u32x4 pw; pw[0] = w0; pw[1] = w1; pw[2] = w2; pw[3] = w3;                    \
            const bf16x8 pf = __builtin_bit_cast(bf16x8, pw);                            \
            const char* vb = ldsR[2 * ((c) & 1) + ktl] + (VB_) + ((c) >> 1) * 8192;      \
            const bf16x8 vf0 = *(const bf16x8*)vb;                                       \
            const bf16x8 vf1 = *(const bf16x8*)(vb + 4096);                              \
            o0 = __builtin_amdgcn_mfma_f32_32x32x16_bf16(vf0, pf, o0, 0, 0, 0);          \
            o1 = __builtin_amdgcn_mfma_f32_32x32x16_bf16(vf1, pf, o1, 0, 0, 0);          \
        }                                                                                \
        __builtin_amdgcn_s_setprio(0);                                                   \
    }

#define ATTN_ITER(KB_, VB_, PKB_, PVB_, DO_PREF)                                         \
    {                                                                                    \
        __syncthreads();                                                                 \
        if (DO_PREF) STAGE(PKB_, PVB_);                                                  \
        __builtin_amdgcn_s_setprio(1);                                                   \
        QK(KB_, sA, 0); QK(KB_, sB, 1); QK(KB_, sC, 2); QK(KB_, sD, 3);                  \
        __builtin_amdgcn_s_setprio(0);                                                   \
        SMPV(sA, 0, VB_); SMPV(sB, 1, VB_); SMPV(sC, 2, VB_); SMPV(sD, 3, VB_);          \
    }

    STAGE(0, 32768);
    for (int it = 0; it < 16; it += 2) {
        ATTN_ITER(0, 32768, 16384, 49152, true);
        ATTN_ITER(16384, 49152, 0, 32768, (it + 2 < 16));
    }
#undef ATTN_ITER
#undef SMPV
#undef QK
#undef STAGE

    const float lt = l_part + __shfl_xor(l_part, 32);
    const float inv = 1.0f / lt;

    __syncthreads();   // done with K/V LDS; reuse as per-wave epilogue scratch

    // O^T -> O transpose via LDS (hi at wid*8K, lo at +4K), swizzled rows
    char* ehi = smem + wid * 8192;
    char* elo = ehi + 4096;
    #pragma unroll
    for (int db = 0; db < 2; ++db) {
        #pragma unroll
        for (int rr = 0; rr < 4; ++rr) {
            float v0, v1, v2, v3;
            if (db == 0) {
                v0 = o0[4 * rr + 0] * inv; v1 = o0[4 * rr + 1] * inv;
                v2 = o0[4 * rr + 2] * inv; v3 = o0[4 * rr + 3] * inv;
            } else {
                v0 = o1[4 * rr + 0] * inv; v1 = o1[4 * rr + 1] * inv;
                v2 = o1[4 * rr + 2] * inv; v3 = o1[4 * rr + 3] * inv;
            }
            u32x2 wh, wl;
            wh.x = cvtpk_bf16(v0, v1);
            wh.y = cvtpk_bf16(v2, v3);
            const float r0 = v0 - __uint_as_float(wh.x << 16);
            const float r1 = v1 - __uint_as_float(wh.x & 0xFFFF0000u);
            const float r2 = v2 - __uint_as_float(wh.y << 16);
            const float r3 = v3 - __uint_as_float(wh.y & 0xFFFF0000u);
            wl.x = cvtpk_bf16(r0, r1);
            wl.y = cvtpk_bf16(r2, r3);
            // row q=l, byte col = 64db + 16rr + 8h -> granule 4db+rr, in-granule 8h
            const int byteoff = l * 128 + (((4 * db + rr) ^ (l & 7)) << 4) + 8 * h;
            *(u32x2*)(ehi + byteoff) = wh;
            *(u32x2*)(elo + byteoff) = wl;
        }
    }
    // per-wave private region: lgkmcnt ordering suffices, no barrier

    const int b = bh >> 4, head = bh & 15;
    const int sub = lane & 7;
    const int row8 = lane >> 3;
    #pragma unroll
    for (int rr = 0; rr < 4; ++rr) {
        const int row = 8 * rr + row8;
        const int byteoff = row * 128 + ((sub ^ row8) << 4);
        const size_t gidx = ((size_t)b * T_ + q0 + row) * DM_ + head * 64 + sub * 8;
        *(u32x4*)(Ah + gidx) = *(const u32x4*)(ehi + byteoff);
        *(u32x4*)(Al + gidx) = *(const u32x4*)(elo + byteoff);
    }
}

// ---------------- Output projection: split-bf16 MFMA GEMM, 8 waves, dbuf ----------------
__global__ __launch_bounds__(512) void proj_mfma(
    const u16* __restrict__ Ah, const u16* __restrict__ Al,
    const u16* __restrict__ Wh, const u16* __restrict__ Wl,
    const float* __restrict__ bp, float* __restrict__ out)
{
    __shared__ char smem[131072];  // 2 x {Ah,Al,Wh,Wl} of 128x64 bf16 (16KB each)

    const int tid = threadIdx.x;
    const int wid = tid >> 6;      // 0..7
    const int lane = tid & 63;
    const int li = lane & 15, g = lane >> 4;
    const int row0 = blockIdx.y * 128, col0 = blockIdx.x * 128;

    const int mat = wid >> 1, half = wid & 1;
    const char* gsrc;
    if (mat == 0)      gsrc = (const char*)(Ah + (size_t)row0 * DM_);
    else if (mat == 1) gsrc = (const char*)(Al + (size_t)row0 * DM_);
    else if (mat == 2) gsrc = (const char*)(Wh + (size_t)col0 * DM_);
    else               gsrc = (const char*)(Wl + (size_t)col0 * DM_);
    const int r_local = half * 64 + (lane >> 3);
    const int c16s = (lane & 7) ^ (lane >> 3);
    const char* gp0 = gsrc + (size_t)r_local * (DM_ * 2) + (c16s << 4);
    const int ldst0 = mat * 16384 + half * 8192;

#define PSTAGE(BUF, STEP)                                                                \
    {                                                                                    \
        _Pragma("unroll")                                                                \
        for (int j = 0; j < 8; ++j) {                                                    \
            __builtin_amdgcn_global_load_lds(                                            \
                (const __attribute__((address_space(1))) u32*)(gp0 + (size_t)(STEP) * 128 + (size_t)j * (8 * DM_ * 2)), \
                (__attribute__((address_space(3))) u32*)(smem + (BUF) + ldst0 + j * 1024),\
                16, 0, 0);                                                               \
        }                                                                                \
    }

    const int wr = wid >> 1, wc = wid & 1;

    f32x4 acc[2][4];
    #pragma unroll
    for (int m = 0; m < 2; ++m)
        #pragma unroll
        for (int n = 0; n < 4; ++n) acc[m][n] = (f32x4){0.f, 0.f, 0.f, 0.f};

    PSTAGE(0, 0);
    for (int step = 0; step < 16; ++step) {
        const int buf = (step & 1) * 65536;
        __syncthreads();
        if (step < 15) PSTAGE(buf ^ 65536, step + 1);

        const u16* pAh = (const u16*)(smem + buf);
        const u16* pAl = (const u16*)(smem + buf + 16384);
        const u16* pWh = (const u16*)(smem + buf + 32768);
        const u16* pWl = (const u16*)(smem + buf + 49152);

        __builtin_amdgcn_s_setprio(1);
        #pragma unroll
        for (int kt = 0; kt < 2; ++kt) {
            bf16x8 ah[2], al[2], wh[4], wl[4];
            #pragma unroll
            for (int m = 0; m < 2; ++m) {
                ah[m] = *frag_at(pAh, wr * 32 + m * 16 + li, kt * 4 + g);
                al[m] = *frag_at(pAl, wr * 32 + m * 16 + li, kt * 4 + g);
            }
            #pragma unroll
            for (int n = 0; n < 4; ++n) {
                wh[n] = *frag_at(pWh, wc * 64 + n * 16 + li, kt * 4 + g);
                wl[n] = *frag_at(pWl, wc * 64 + n * 16 + li, kt * 4 + g);
            }
            #pragma unroll
            for (int m = 0; m < 2; ++m)
                #pragma unroll
                for (int n = 0; n < 4; ++n) {
                    acc[m][n] = __builtin_amdgcn_mfma_f32_16x16x32_bf16(ah[m], wh[n], acc[m][n], 0, 0, 0);
                    acc[m][n] = __builtin_amdgcn_mfma_f32_16x16x32_bf16(al[m], wh[n], acc[m][n], 0, 0, 0);
                    acc[m][n] = __builtin_amdgcn_mfma_f32_16x16x32_bf16(ah[m], wl[n], acc[m][n], 0, 0, 0);
                }
        }
        __builtin_amdgcn_s_setprio(0);
    }
#undef PSTAGE

    const int orow = row0 + wr * 32;
    const int ocol = col0 + wc * 64;
    float bias[4];
    #pragma unroll
    for (int n = 0; n < 4; ++n) bias[n] = bp[ocol + n * 16 + li];
    #pragma unroll
    for (int m = 0; m < 2; ++m)
        #pragma unroll
        for (int n = 0; n < 4; ++n)
            #pragma unroll
            for (int q = 0; q < 4; ++q)
                out[(size_t)(orow + m * 16 + g * 4 + q) * DM_ + ocol + n * 16 + li] =
                    acc[m][n][q] + bias[n];
}

extern "C" void kernel_launch(void* const* d_in, const int* in_sizes, int n_in,
                              void* d_out, int out_size, void* d_ws, size_t ws_size,
                              hipStream_t stream) {
    const float* x  = (const float*)d_in[0];
    const float* Wq = (const float*)d_in[1];
    const float* bq = (const float*)d_in[2];
    const float* Wk = (const float*)d_in[3];
    const float* bk = (const float*)d_in[4];
    const float* Wv = (const float*)d_in[5];
    const float* bv = (const float*)d_in[6];
    const float* Wp = (const float*)d_in[7];
    const float* bp = (const float*)d_in[8];
    float* out = (float*)d_out;

    const size_t n_qkv = (size_t)B_ * H_ * T_ * DH_;   // 4,194,304
    const size_t n_w   = (size_t)DM_ * DM_;            // 1,048,576
    u16* Qb  = (u16*)d_ws;
    u16* Kb  = Qb + n_qkv;
    u16* VTb = Kb + n_qkv;
    u16* Ahb = VTb + n_qkv;
    u16* Alb = Ahb + n_qkv;
    u16* Whb = Alb + n_qkv;
    u16* Wlb = Whb + n_w;
    u16* W6b = Wlb + n_w;      // 6 * 4096 u16

    wsplit_all<<<(n_w + 12288) / 256, 256, 0, stream>>>(Wq, Wk, Wv, Wp, W6b, Whb, Wlb);
    qkv_mfma<<<32 * 16, 256, 0, stream>>>(x, bq, bk, bv, W6b, Qb, Kb, VTb);
    attn_mfma<<<512, 256, 0, stream>>>(Qb, Kb, VTb, Ahb, Alb);
    proj_mfma<<<dim3(DM_ / 128, (B_ * T_) / 128), 512, 0, stream>>>(Ahb, Alb, Whb, Wlb, bp, out);
}